// Round 3
// baseline (499.288 us; speedup 1.0000x reference)
//
#include <hip/hip_runtime.h>
#include <math.h>

#define NE   2048
#define FEAT 512

typedef short short8 __attribute__((ext_vector_type(8)));
typedef float f32x4  __attribute__((ext_vector_type(4)));

__device__ __forceinline__ unsigned short f2bf(float f) {
    union { float f; unsigned u; } v; v.f = f;
    unsigned r = v.u + 0x7fffu + ((v.u >> 16) & 1u);   // RNE
    return (unsigned short)(r >> 16);
}
__device__ __forceinline__ float bf2f(unsigned b) {
    union { unsigned u; float f; } v; v.u = b << 16;
    return v.f;
}
__device__ __forceinline__ unsigned pack2(float a, float b) {
    return (unsigned)f2bf(a) | ((unsigned)f2bf(b) << 16);
}

// ---------------------------------------------------------------------------
// K0: x[n][f][r] fp32 -> xt[(n*8+r)][f] bf16
// ---------------------------------------------------------------------------
__global__ __launch_bounds__(256) void xpose_kernel(const float* __restrict__ x,
                                                    unsigned short* __restrict__ xt)
{
    __shared__ float xs[8 * 516];
    const int t = threadIdx.x;
    const int n = blockIdx.x;
    const float4* xp = (const float4*)(x + (size_t)n * 4096);
    #pragma unroll
    for (int i = 0; i < 4; ++i) {
        int idx = t + 256 * i;
        float4 v = xp[idx];
        int f = idx >> 1, rh = (idx & 1) * 4;
        xs[(rh + 0) * 516 + f] = v.x;
        xs[(rh + 1) * 516 + f] = v.y;
        xs[(rh + 2) * 516 + f] = v.z;
        xs[(rh + 3) * 516 + f] = v.w;
    }
    __syncthreads();
    const int r = t >> 5, f0 = (t & 31) * 16;
    const float* src = &xs[r * 516 + f0];
    unsigned o[8];
    #pragma unroll
    for (int j = 0; j < 8; ++j) o[j] = pack2(src[2 * j], src[2 * j + 1]);
    unsigned short* dst = xt + (size_t)n * 4096 + r * 512 + f0;
    *(uint4*)dst       = make_uint4(o[0], o[1], o[2], o[3]);
    *(uint4*)(dst + 8) = make_uint4(o[4], o[5], o[6], o[7]);
}

// ---------------------------------------------------------------------------
// K1: proj GEMM -> qb/kb/db [h][n][l*8+r] bf16  (unchanged from R2)
// ---------------------------------------------------------------------------
__global__ __launch_bounds__(256) void proj_gemm(
    const float* __restrict__ Wq, const float* __restrict__ Wk, const float* __restrict__ Wd,
    const unsigned short* __restrict__ xt,
    unsigned short* __restrict__ qb, unsigned short* __restrict__ kb, unsigned short* __restrict__ db)
{
    __shared__ unsigned short As[128 * 72];
    __shared__ unsigned short Bs[128 * 72];
    const int t = threadIdx.x;
    const int w = blockIdx.z;
    const float* W = (w == 0) ? Wq : (w == 1) ? Wk : Wd;
    unsigned short* out = (w == 0) ? qb : (w == 1) ? kb : db;
    const int M0 = blockIdx.y * 128;
    const int N0 = blockIdx.x * 128;
    const int wave = t >> 6, lane = t & 63;
    const int quad = lane >> 4, l16 = lane & 15;

    f32x4 acc[2][8];
    #pragma unroll
    for (int i = 0; i < 2; ++i)
        #pragma unroll
        for (int j = 0; j < 8; ++j) acc[i][j] = {0.f, 0.f, 0.f, 0.f};

    const int ar = t >> 2, afs = (t & 3) * 16;
    const int br = t >> 3, bcs = (t & 7) * 8;

    for (int kc = 0; kc < 8; ++kc) {
        #pragma unroll
        for (int p = 0; p < 2; ++p) {
            int row = ar + p * 64;
            const float4* g = (const float4*)(W + (size_t)(M0 + row) * 512 + kc * 64 + afs);
            float4 v0 = g[0], v1 = g[1], v2 = g[2], v3 = g[3];
            unsigned short* d = &As[row * 72 + afs];
            *(uint4*)d       = make_uint4(pack2(v0.x, v0.y), pack2(v0.z, v0.w),
                                          pack2(v1.x, v1.y), pack2(v1.z, v1.w));
            *(uint4*)(d + 8) = make_uint4(pack2(v2.x, v2.y), pack2(v2.z, v2.w),
                                          pack2(v3.x, v3.y), pack2(v3.z, v3.w));
        }
        #pragma unroll
        for (int p = 0; p < 4; ++p) {
            int row = br + p * 32;
            *(uint4*)&Bs[row * 72 + bcs] =
                *(const uint4*)(xt + (size_t)(N0 + row) * 512 + kc * 64 + bcs);
        }
        __syncthreads();
        #pragma unroll
        for (int kk = 0; kk < 2; ++kk) {
            short8 a0 = *(const short8*)&As[(wave * 32 + l16) * 72 + kk * 32 + quad * 8];
            short8 a1 = *(const short8*)&As[(wave * 32 + 16 + l16) * 72 + kk * 32 + quad * 8];
            #pragma unroll
            for (int ct = 0; ct < 8; ++ct) {
                short8 b = *(const short8*)&Bs[(ct * 16 + l16) * 72 + kk * 32 + quad * 8];
                acc[0][ct] = __builtin_amdgcn_mfma_f32_16x16x32_bf16(a0, b, acc[0][ct], 0, 0, 0);
                acc[1][ct] = __builtin_amdgcn_mfma_f32_16x16x32_bf16(a1, b, acc[1][ct], 0, 0, 0);
            }
        }
        __syncthreads();
    }
    #pragma unroll
    for (int rt = 0; rt < 2; ++rt)
        #pragma unroll
        for (int reg = 0; reg < 4; ++reg) {
            int hl = M0 + wave * 32 + rt * 16 + quad * 4 + reg;
            size_t rowbase = (size_t)(hl >> 6) * 1048576 + (size_t)(hl & 63) * 8;
            #pragma unroll
            for (int ct = 0; ct < 8; ++ct) {
                int col = N0 + ct * 16 + l16;
                out[rowbase + (size_t)(col >> 3) * 512 + (col & 7)] = f2bf(acc[rt][ct][reg]);
            }
        }
}

// ---------------------------------------------------------------------------
// K1.6: scales[w][n] = rsqrt(sum over (h,l,r) of y^2)
// ---------------------------------------------------------------------------
__global__ __launch_bounds__(256) void scales_kernel(
    const unsigned short* __restrict__ qb, const unsigned short* __restrict__ kb,
    const unsigned short* __restrict__ db, float* __restrict__ scales)
{
    __shared__ float red[256];
    const int t = threadIdx.x;
    const int n = blockIdx.x, w = blockIdx.y;
    const unsigned short* src = (w == 0) ? qb : (w == 1) ? kb : db;
    const int h = t >> 5, f0 = (t & 31) * 16;
    const unsigned short* p = src + ((size_t)h * NE + n) * 512 + f0;
    uint4 v0 = *(const uint4*)p;
    uint4 v1 = *(const uint4*)(p + 8);
    unsigned a[8] = {v0.x, v0.y, v0.z, v0.w, v1.x, v1.y, v1.z, v1.w};
    float s = 0.f;
    #pragma unroll
    for (int j = 0; j < 8; ++j) {
        float lo = bf2f(a[j] & 0xffffu), hi = bf2f(a[j] >> 16);
        s += lo * lo + hi * hi;
    }
    red[t] = s;
    __syncthreads();
    for (int st = 128; st > 0; st >>= 1) {
        if (t < st) red[t] += red[t + st];
        __syncthreads();
    }
    if (t == 0) scales[w * NE + n] = rsqrtf(red[0]);
}

// ---------------------------------------------------------------------------
// K1.5: dT[h][f][n] = db[h][n][f] * invd[n]
// ---------------------------------------------------------------------------
__global__ __launch_bounds__(256) void dtrans_kernel(
    const unsigned short* __restrict__ db, const float* __restrict__ invd,
    unsigned short* __restrict__ dT)
{
    __shared__ float Ts[64 * 68];
    const int t = threadIdx.x;
    const int h = blockIdx.z, n0 = blockIdx.y * 64, f0 = blockIdx.x * 64;
    const int rr = t >> 3, cs = (t & 7) * 8;
    #pragma unroll
    for (int p = 0; p < 2; ++p) {
        int row = rr + p * 32;
        float sc = invd[n0 + row];
        uint4 v = *(const uint4*)(db + ((size_t)h * NE + n0 + row) * 512 + f0 + cs);
        unsigned a[4] = {v.x, v.y, v.z, v.w};
        float* d = &Ts[row * 68 + cs];
        #pragma unroll
        for (int j = 0; j < 4; ++j) {
            d[2 * j]     = bf2f(a[j] & 0xffffu) * sc;
            d[2 * j + 1] = bf2f(a[j] >> 16) * sc;
        }
    }
    __syncthreads();
    const int f = t >> 2, ns = (t & 3) * 16;
    unsigned o[8];
    #pragma unroll
    for (int j = 0; j < 8; ++j)
        o[j] = pack2(Ts[(ns + 2 * j) * 68 + f], Ts[(ns + 2 * j + 1) * 68 + f]);
    unsigned short* dst = dT + ((size_t)h * 512 + f0 + f) * NE + n0 + ns;
    *(uint4*)dst       = make_uint4(o[0], o[1], o[2], o[3]);
    *(uint4*)(dst + 8) = make_uint4(o[4], o[5], o[6], o[7]);
}

// ---------------------------------------------------------------------------
// K2a: scores -> exp -> P bf16, plus per-row exp-sums atomically into lbuf.
// Double-buffered LDS staging. |s|<=1 so no max subtraction.
// ---------------------------------------------------------------------------
__global__ __launch_bounds__(256) void score_kernel(
    const unsigned short* __restrict__ qb, const unsigned short* __restrict__ kb,
    const float* __restrict__ scales, unsigned short* __restrict__ P,
    float* __restrict__ lbuf, int g)
{
    __shared__ unsigned short As[2][128 * 72];
    __shared__ unsigned short Bs[2][128 * 72];
    const int t = threadIdx.x;
    const int hg = blockIdx.z, h = g * 4 + hg;
    const int n0 = blockIdx.y * 128, m0 = blockIdx.x * 128;
    const int wave = t >> 6, lane = t & 63, quad = lane >> 4, l16 = lane & 15;
    const unsigned short* qh = qb + (size_t)h * NE * 512;
    const unsigned short* kh = kb + (size_t)h * NE * 512;
    const int br = t >> 3, bcs = (t & 7) * 8;

    f32x4 acc[2][8];
    #pragma unroll
    for (int i = 0; i < 2; ++i)
        #pragma unroll
        for (int j = 0; j < 8; ++j) acc[i][j] = {0.f, 0.f, 0.f, 0.f};

    uint4 av[4], bv[4];
    #pragma unroll
    for (int p = 0; p < 4; ++p) {
        av[p] = *(const uint4*)(qh + (size_t)(n0 + br + p * 32) * 512 + bcs);
        bv[p] = *(const uint4*)(kh + (size_t)(m0 + br + p * 32) * 512 + bcs);
    }
    #pragma unroll
    for (int p = 0; p < 4; ++p) {
        *(uint4*)&As[0][(br + p * 32) * 72 + bcs] = av[p];
        *(uint4*)&Bs[0][(br + p * 32) * 72 + bcs] = bv[p];
    }
    __syncthreads();

    for (int kc = 0; kc < 8; ++kc) {
        const int cur = kc & 1;
        if (kc < 7) {
            #pragma unroll
            for (int p = 0; p < 4; ++p) {
                av[p] = *(const uint4*)(qh + (size_t)(n0 + br + p * 32) * 512 + (kc + 1) * 64 + bcs);
                bv[p] = *(const uint4*)(kh + (size_t)(m0 + br + p * 32) * 512 + (kc + 1) * 64 + bcs);
            }
        }
        #pragma unroll
        for (int kk = 0; kk < 2; ++kk) {
            short8 a0 = *(const short8*)&As[cur][(wave * 32 + l16) * 72 + kk * 32 + quad * 8];
            short8 a1 = *(const short8*)&As[cur][(wave * 32 + 16 + l16) * 72 + kk * 32 + quad * 8];
            #pragma unroll
            for (int ct = 0; ct < 8; ++ct) {
                short8 b = *(const short8*)&Bs[cur][(ct * 16 + l16) * 72 + kk * 32 + quad * 8];
                acc[0][ct] = __builtin_amdgcn_mfma_f32_16x16x32_bf16(a0, b, acc[0][ct], 0, 0, 0);
                acc[1][ct] = __builtin_amdgcn_mfma_f32_16x16x32_bf16(a1, b, acc[1][ct], 0, 0, 0);
            }
        }
        if (kc < 7) {
            __syncthreads();
            #pragma unroll
            for (int p = 0; p < 4; ++p) {
                *(uint4*)&As[1 - cur][(br + p * 32) * 72 + bcs] = av[p];
                *(uint4*)&Bs[1 - cur][(br + p * 32) * 72 + bcs] = bv[p];
            }
            __syncthreads();
        }
    }

    float iq[2][4], ik[8];
    #pragma unroll
    for (int rt = 0; rt < 2; ++rt)
        #pragma unroll
        for (int reg = 0; reg < 4; ++reg)
            iq[rt][reg] = scales[n0 + wave * 32 + rt * 16 + quad * 4 + reg];
    #pragma unroll
    for (int ct = 0; ct < 8; ++ct) ik[ct] = scales[NE + m0 + ct * 16 + l16];

    unsigned short* Ph = P + (size_t)hg * NE * NE;
    #pragma unroll
    for (int rt = 0; rt < 2; ++rt) {
        #pragma unroll
        for (int reg = 0; reg < 4; ++reg) {
            int nl = wave * 32 + rt * 16 + quad * 4 + reg;
            unsigned short* prow = Ph + (size_t)(n0 + nl) * NE + m0;
            float qs = iq[rt][reg];
            float rs = 0.f;
            #pragma unroll
            for (int ct = 0; ct < 8; ++ct) {
                float e = __expf(acc[rt][ct][reg] * qs * ik[ct]);
                prow[ct * 16 + l16] = f2bf(e);
                rs += e;
            }
            #pragma unroll
            for (int msk = 8; msk >= 1; msk >>= 1) rs += __shfl_xor(rs, msk, 16);
            if (l16 == 0) atomicAdd(&lbuf[(size_t)h * NE + n0 + nl], rs);
        }
    }
}

// ---------------------------------------------------------------------------
// K2b: V[n][f] = (sum_m P[n][m] * dT[f][m]) / l[n]
// 64n x 128f tile, K=2048 in chunks of 64, double-buffered staging.
// ---------------------------------------------------------------------------
__global__ __launch_bounds__(256) void combine_kernel(
    const unsigned short* __restrict__ P, const unsigned short* __restrict__ dT,
    const float* __restrict__ lbuf, float* __restrict__ out, int g)
{
    __shared__ unsigned short Ps[2][64 * 72];
    __shared__ unsigned short Ds[2][128 * 72];
    const int t = threadIdx.x;
    const int hg = blockIdx.z, h = g * 4 + hg;
    const int n0 = blockIdx.y * 64, f0 = blockIdx.x * 128;
    const int wave = t >> 6, lane = t & 63, quad = lane >> 4, l16 = lane & 15;
    const unsigned short* Ph = P + (size_t)hg * NE * NE;
    const unsigned short* dh = dT + (size_t)h * 512 * NE;
    const int br = t >> 3, bcs = (t & 7) * 8;

    f32x4 acc[8];
    #pragma unroll
    for (int j = 0; j < 8; ++j) acc[j] = {0.f, 0.f, 0.f, 0.f};

    uint4 pv[2], dv[4];
    #pragma unroll
    for (int p = 0; p < 2; ++p)
        pv[p] = *(const uint4*)(Ph + (size_t)(n0 + br + p * 32) * NE + bcs);
    #pragma unroll
    for (int p = 0; p < 4; ++p)
        dv[p] = *(const uint4*)(dh + (size_t)(f0 + br + p * 32) * NE + bcs);
    #pragma unroll
    for (int p = 0; p < 2; ++p) *(uint4*)&Ps[0][(br + p * 32) * 72 + bcs] = pv[p];
    #pragma unroll
    for (int p = 0; p < 4; ++p) *(uint4*)&Ds[0][(br + p * 32) * 72 + bcs] = dv[p];
    __syncthreads();

    for (int mc = 0; mc < 32; ++mc) {
        const int cur = mc & 1;
        if (mc < 31) {
            #pragma unroll
            for (int p = 0; p < 2; ++p)
                pv[p] = *(const uint4*)(Ph + (size_t)(n0 + br + p * 32) * NE + (mc + 1) * 64 + bcs);
            #pragma unroll
            for (int p = 0; p < 4; ++p)
                dv[p] = *(const uint4*)(dh + (size_t)(f0 + br + p * 32) * NE + (mc + 1) * 64 + bcs);
        }
        #pragma unroll
        for (int kk = 0; kk < 2; ++kk) {
            short8 a = *(const short8*)&Ps[cur][(wave * 16 + l16) * 72 + kk * 32 + quad * 8];
            #pragma unroll
            for (int ct = 0; ct < 8; ++ct) {
                short8 b = *(const short8*)&Ds[cur][(ct * 16 + l16) * 72 + kk * 32 + quad * 8];
                acc[ct] = __builtin_amdgcn_mfma_f32_16x16x32_bf16(a, b, acc[ct], 0, 0, 0);
            }
        }
        if (mc < 31) {
            __syncthreads();
            #pragma unroll
            for (int p = 0; p < 2; ++p) *(uint4*)&Ps[1 - cur][(br + p * 32) * 72 + bcs] = pv[p];
            #pragma unroll
            for (int p = 0; p < 4; ++p) *(uint4*)&Ds[1 - cur][(br + p * 32) * 72 + bcs] = dv[p];
            __syncthreads();
        }
    }

    const int nl = wave * 16 + quad * 4;
    #pragma unroll
    for (int reg = 0; reg < 4; ++reg) {
        float inv = 1.0f / lbuf[(size_t)h * NE + n0 + nl + reg];
        float* orow = out + (size_t)(n0 + nl + reg) * 4096 + h * 512 + f0;
        #pragma unroll
        for (int ct = 0; ct < 8; ++ct)
            orow[ct * 16 + l16] = acc[ct][reg] * inv;
    }
}

extern "C" void kernel_launch(void* const* d_in, const int* in_sizes, int n_in,
                              void* d_out, int out_size, void* d_ws, size_t ws_size,
                              hipStream_t stream)
{
    const float* x  = (const float*)d_in[0];
    const float* Qw = (const float*)d_in[1];
    const float* Kw = (const float*)d_in[2];
    const float* Dw = (const float*)d_in[3];
    float* out = (float*)d_out;

    char* ws = (char*)d_ws;
    unsigned short* xt = (unsigned short*)ws;                             // 16 MB
    unsigned short* db = (unsigned short*)(ws + 16777216);                // 16 MB
    unsigned short* P  = (unsigned short*)ws;                             // 32 MB (reuse xt+db)
    unsigned short* qb = (unsigned short*)(ws + 33554432);                // 16 MB
    unsigned short* kb = (unsigned short*)(ws + 33554432 + 16777216);     // 16 MB
    unsigned short* dT = (unsigned short*)(ws + 33554432 + 2 * 16777216); // 16 MB
    float* scales = (float*)(ws + 83886080);                              // 24 KB
    float* lbuf   = (float*)(ws + 83886080 + 32768);                      // 64 KB

    hipMemsetAsync(lbuf, 0, 8 * NE * sizeof(float), stream);
    xpose_kernel<<<2048, 256, 0, stream>>>(x, xt);
    proj_gemm<<<dim3(128, 4, 3), 256, 0, stream>>>(Qw, Kw, Dw, xt, qb, kb, db);
    scales_kernel<<<dim3(2048, 3), 256, 0, stream>>>(qb, kb, db, scales);
    dtrans_kernel<<<dim3(8, 32, 8), 256, 0, stream>>>(db, scales + 2 * NE, dT);
    for (int g = 0; g < 2; ++g) {
        score_kernel<<<dim3(16, 16, 4), 256, 0, stream>>>(qb, kb, scales, P, lbuf, g);
        combine_kernel<<<dim3(4, 32, 4), 256, 0, stream>>>(P, dT, lbuf, out, g);
    }
}

// Round 4
// 422.667 us; speedup vs baseline: 1.1813x; 1.1813x over previous
//
#include <hip/hip_runtime.h>
#include <math.h>

#define NE   2048
#define FEAT 512

typedef short short8 __attribute__((ext_vector_type(8)));
typedef float f32x4  __attribute__((ext_vector_type(4)));

__device__ __forceinline__ unsigned short f2bf(float f) {
    union { float f; unsigned u; } v; v.f = f;
    unsigned r = v.u + 0x7fffu + ((v.u >> 16) & 1u);   // RNE
    return (unsigned short)(r >> 16);
}
__device__ __forceinline__ float bf2f(unsigned b) {
    union { unsigned u; float f; } v; v.u = b << 16;
    return v.f;
}
__device__ __forceinline__ unsigned pack2(float a, float b) {
    return (unsigned)f2bf(a) | ((unsigned)f2bf(b) << 16);
}

// ---------------------------------------------------------------------------
// K0: x[n][f][r] fp32 -> xt[(n*8+r)][f] bf16
// ---------------------------------------------------------------------------
__global__ __launch_bounds__(256) void xpose_kernel(const float* __restrict__ x,
                                                    unsigned short* __restrict__ xt)
{
    __shared__ float xs[8 * 516];
    const int t = threadIdx.x;
    const int n = blockIdx.x;
    const float4* xp = (const float4*)(x + (size_t)n * 4096);
    #pragma unroll
    for (int i = 0; i < 4; ++i) {
        int idx = t + 256 * i;
        float4 v = xp[idx];
        int f = idx >> 1, rh = (idx & 1) * 4;
        xs[(rh + 0) * 516 + f] = v.x;
        xs[(rh + 1) * 516 + f] = v.y;
        xs[(rh + 2) * 516 + f] = v.z;
        xs[(rh + 3) * 516 + f] = v.w;
    }
    __syncthreads();
    const int r = t >> 5, f0 = (t & 31) * 16;
    const float* src = &xs[r * 516 + f0];
    unsigned o[8];
    #pragma unroll
    for (int j = 0; j < 8; ++j) o[j] = pack2(src[2 * j], src[2 * j + 1]);
    unsigned short* dst = xt + (size_t)n * 4096 + r * 512 + f0;
    *(uint4*)dst       = make_uint4(o[0], o[1], o[2], o[3]);
    *(uint4*)(dst + 8) = make_uint4(o[4], o[5], o[6], o[7]);
}

// ---------------------------------------------------------------------------
// K1: proj GEMM -> qb/kb/db [h][n][l*8+r] bf16.  Single-buffered K-loop,
// LDS-bounce epilogue for fully-coalesced 1KB-row writes (kills the 2B-scatter
// write amplification seen in rocprof).
// ---------------------------------------------------------------------------
__global__ __launch_bounds__(256) void proj_gemm(
    const float* __restrict__ Wq, const float* __restrict__ Wk, const float* __restrict__ Wd,
    const unsigned short* __restrict__ xt,
    unsigned short* __restrict__ qb, unsigned short* __restrict__ kb, unsigned short* __restrict__ db)
{
    __shared__ unsigned short smem[2 * 128 * 72];   // As | Bs, re-used as C-tile
    unsigned short* As = smem;
    unsigned short* Bs = smem + 128 * 72;
    unsigned short* Cs = smem;                      // 128 x 136 bf16 = 34.8 KB

    const int t = threadIdx.x;
    const int w = blockIdx.z;
    const float* W = (w == 0) ? Wq : (w == 1) ? Wk : Wd;
    unsigned short* out = (w == 0) ? qb : (w == 1) ? kb : db;
    const int M0 = blockIdx.y * 128;
    const int N0 = blockIdx.x * 128;
    const int wave = t >> 6, lane = t & 63;
    const int quad = lane >> 4, l16 = lane & 15;

    f32x4 acc[2][8];
    #pragma unroll
    for (int i = 0; i < 2; ++i)
        #pragma unroll
        for (int j = 0; j < 8; ++j) acc[i][j] = {0.f, 0.f, 0.f, 0.f};

    const int ar = t >> 2, afs = (t & 3) * 16;
    const int br = t >> 3, bcs = (t & 7) * 8;

    for (int kc = 0; kc < 8; ++kc) {
        #pragma unroll
        for (int p = 0; p < 2; ++p) {
            int row = ar + p * 64;
            const float4* g = (const float4*)(W + (size_t)(M0 + row) * 512 + kc * 64 + afs);
            float4 v0 = g[0], v1 = g[1], v2 = g[2], v3 = g[3];
            unsigned short* d = &As[row * 72 + afs];
            *(uint4*)d       = make_uint4(pack2(v0.x, v0.y), pack2(v0.z, v0.w),
                                          pack2(v1.x, v1.y), pack2(v1.z, v1.w));
            *(uint4*)(d + 8) = make_uint4(pack2(v2.x, v2.y), pack2(v2.z, v2.w),
                                          pack2(v3.x, v3.y), pack2(v3.z, v3.w));
        }
        #pragma unroll
        for (int p = 0; p < 4; ++p) {
            int row = br + p * 32;
            *(uint4*)&Bs[row * 72 + bcs] =
                *(const uint4*)(xt + (size_t)(N0 + row) * 512 + kc * 64 + bcs);
        }
        __syncthreads();
        #pragma unroll
        for (int kk = 0; kk < 2; ++kk) {
            short8 a0 = *(const short8*)&As[(wave * 32 + l16) * 72 + kk * 32 + quad * 8];
            short8 a1 = *(const short8*)&As[(wave * 32 + 16 + l16) * 72 + kk * 32 + quad * 8];
            #pragma unroll
            for (int ct = 0; ct < 8; ++ct) {
                short8 b = *(const short8*)&Bs[(ct * 16 + l16) * 72 + kk * 32 + quad * 8];
                acc[0][ct] = __builtin_amdgcn_mfma_f32_16x16x32_bf16(a0, b, acc[0][ct], 0, 0, 0);
                acc[1][ct] = __builtin_amdgcn_mfma_f32_16x16x32_bf16(a1, b, acc[1][ct], 0, 0, 0);
            }
        }
        __syncthreads();
    }
    // ---- epilogue: C-tile -> LDS -> coalesced global ----
    #pragma unroll
    for (int rt = 0; rt < 2; ++rt)
        #pragma unroll
        for (int reg = 0; reg < 4; ++reg) {
            int rloc = wave * 32 + rt * 16 + quad * 4 + reg;
            #pragma unroll
            for (int ct = 0; ct < 8; ++ct)
                Cs[rloc * 136 + ct * 16 + l16] = f2bf(acc[rt][ct][reg]);
        }
    __syncthreads();
    // block covers heads h0,h0+1 fully; out rows (h,n) are 512-elem contiguous
    const int h0 = blockIdx.y * 2, n0g = blockIdx.x * 16;
    const int hn = t >> 3, lg = t & 7;
    const int hh = hn >> 4, nn = hn & 15;
    unsigned short* dst = out + ((size_t)(h0 + hh) * NE + n0g + nn) * 512 + lg * 64;
    #pragma unroll
    for (int li = 0; li < 8; ++li)
        *(uint4*)(dst + li * 8) = *(const uint4*)&Cs[(hh * 64 + lg * 8 + li) * 136 + nn * 8];
}

// ---------------------------------------------------------------------------
// K1.6: scales[w][n] = rsqrt(sum over (h,l,r) of y^2)
// ---------------------------------------------------------------------------
__global__ __launch_bounds__(256) void scales_kernel(
    const unsigned short* __restrict__ qb, const unsigned short* __restrict__ kb,
    const unsigned short* __restrict__ db, float* __restrict__ scales)
{
    __shared__ float red[256];
    const int t = threadIdx.x;
    const int n = blockIdx.x, w = blockIdx.y;
    const unsigned short* src = (w == 0) ? qb : (w == 1) ? kb : db;
    const int h = t >> 5, f0 = (t & 31) * 16;
    const unsigned short* p = src + ((size_t)h * NE + n) * 512 + f0;
    uint4 v0 = *(const uint4*)p;
    uint4 v1 = *(const uint4*)(p + 8);
    unsigned a[8] = {v0.x, v0.y, v0.z, v0.w, v1.x, v1.y, v1.z, v1.w};
    float s = 0.f;
    #pragma unroll
    for (int j = 0; j < 8; ++j) {
        float lo = bf2f(a[j] & 0xffffu), hi = bf2f(a[j] >> 16);
        s += lo * lo + hi * hi;
    }
    red[t] = s;
    __syncthreads();
    for (int st = 128; st > 0; st >>= 1) {
        if (t < st) red[t] += red[t + st];
        __syncthreads();
    }
    if (t == 0) scales[w * NE + n] = rsqrtf(red[0]);
}

// ---------------------------------------------------------------------------
// K1.5: dT[h][f][n] = db[h][n][f] * invd[n]
// ---------------------------------------------------------------------------
__global__ __launch_bounds__(256) void dtrans_kernel(
    const unsigned short* __restrict__ db, const float* __restrict__ invd,
    unsigned short* __restrict__ dT)
{
    __shared__ float Ts[64 * 68];
    const int t = threadIdx.x;
    const int h = blockIdx.z, n0 = blockIdx.y * 64, f0 = blockIdx.x * 64;
    const int rr = t >> 3, cs = (t & 7) * 8;
    #pragma unroll
    for (int p = 0; p < 2; ++p) {
        int row = rr + p * 32;
        float sc = invd[n0 + row];
        uint4 v = *(const uint4*)(db + ((size_t)h * NE + n0 + row) * 512 + f0 + cs);
        unsigned a[4] = {v.x, v.y, v.z, v.w};
        float* d = &Ts[row * 68 + cs];
        #pragma unroll
        for (int j = 0; j < 4; ++j) {
            d[2 * j]     = bf2f(a[j] & 0xffffu) * sc;
            d[2 * j + 1] = bf2f(a[j] >> 16) * sc;
        }
    }
    __syncthreads();
    const int f = t >> 2, ns = (t & 3) * 16;
    unsigned o[8];
    #pragma unroll
    for (int j = 0; j < 8; ++j)
        o[j] = pack2(Ts[(ns + 2 * j) * 68 + f], Ts[(ns + 2 * j + 1) * 68 + f]);
    unsigned short* dst = dT + ((size_t)h * 512 + f0 + f) * NE + n0 + ns;
    *(uint4*)dst       = make_uint4(o[0], o[1], o[2], o[3]);
    *(uint4*)(dst + 8) = make_uint4(o[4], o[5], o[6], o[7]);
}

// ---------------------------------------------------------------------------
// K2a: scores -> exp -> P bf16 (LDS-bounce coalesced write) + row-sums to lbuf.
// Single-buffered staging. |s|<=1 (unit vectors) so no max subtraction.
// ---------------------------------------------------------------------------
__global__ __launch_bounds__(256) void score_kernel(
    const unsigned short* __restrict__ qb, const unsigned short* __restrict__ kb,
    const float* __restrict__ scales, unsigned short* __restrict__ P,
    float* __restrict__ lbuf, int g)
{
    __shared__ unsigned short smem[2 * 128 * 72];   // As | Bs, re-used as P-tile
    unsigned short* As = smem;
    unsigned short* Bs = smem + 128 * 72;
    unsigned short* Pl = smem;                      // 128 x 136 bf16

    const int t = threadIdx.x;
    const int hg = blockIdx.z, h = g * 4 + hg;
    const int n0 = blockIdx.y * 128, m0 = blockIdx.x * 128;
    const int wave = t >> 6, lane = t & 63, quad = lane >> 4, l16 = lane & 15;
    const unsigned short* qh = qb + (size_t)h * NE * 512;
    const unsigned short* kh = kb + (size_t)h * NE * 512;
    const int br = t >> 3, bcs = (t & 7) * 8;

    f32x4 acc[2][8];
    #pragma unroll
    for (int i = 0; i < 2; ++i)
        #pragma unroll
        for (int j = 0; j < 8; ++j) acc[i][j] = {0.f, 0.f, 0.f, 0.f};

    for (int kc = 0; kc < 8; ++kc) {
        #pragma unroll
        for (int p = 0; p < 4; ++p) {
            int row = br + p * 32;
            *(uint4*)&As[row * 72 + bcs] =
                *(const uint4*)(qh + (size_t)(n0 + row) * 512 + kc * 64 + bcs);
            *(uint4*)&Bs[row * 72 + bcs] =
                *(const uint4*)(kh + (size_t)(m0 + row) * 512 + kc * 64 + bcs);
        }
        __syncthreads();
        #pragma unroll
        for (int kk = 0; kk < 2; ++kk) {
            short8 a0 = *(const short8*)&As[(wave * 32 + l16) * 72 + kk * 32 + quad * 8];
            short8 a1 = *(const short8*)&As[(wave * 32 + 16 + l16) * 72 + kk * 32 + quad * 8];
            #pragma unroll
            for (int ct = 0; ct < 8; ++ct) {
                short8 b = *(const short8*)&Bs[(ct * 16 + l16) * 72 + kk * 32 + quad * 8];
                acc[0][ct] = __builtin_amdgcn_mfma_f32_16x16x32_bf16(a0, b, acc[0][ct], 0, 0, 0);
                acc[1][ct] = __builtin_amdgcn_mfma_f32_16x16x32_bf16(a1, b, acc[1][ct], 0, 0, 0);
            }
        }
        __syncthreads();
    }

    float iq[2][4], ik[8];
    #pragma unroll
    for (int rt = 0; rt < 2; ++rt)
        #pragma unroll
        for (int reg = 0; reg < 4; ++reg)
            iq[rt][reg] = scales[n0 + wave * 32 + rt * 16 + quad * 4 + reg];
    #pragma unroll
    for (int ct = 0; ct < 8; ++ct) ik[ct] = scales[NE + m0 + ct * 16 + l16];

    // exp -> LDS P-tile + row sums (atomic into lbuf)
    #pragma unroll
    for (int rt = 0; rt < 2; ++rt) {
        #pragma unroll
        for (int reg = 0; reg < 4; ++reg) {
            int nl = wave * 32 + rt * 16 + quad * 4 + reg;
            float qs = iq[rt][reg];
            float rs = 0.f;
            #pragma unroll
            for (int ct = 0; ct < 8; ++ct) {
                float e = __expf(acc[rt][ct][reg] * qs * ik[ct]);
                Pl[nl * 136 + ct * 16 + l16] = f2bf(e);
                rs += e;
            }
            #pragma unroll
            for (int msk = 8; msk >= 1; msk >>= 1) rs += __shfl_xor(rs, msk, 16);
            if (l16 == 0) atomicAdd(&lbuf[(size_t)h * NE + n0 + nl], rs);
        }
    }
    __syncthreads();
    // coalesced write: 2 threads per row, 128 B each, full-line aligned
    const int prow = t >> 1, phalf = (t & 1) * 64;
    unsigned short* dst = P + (size_t)hg * NE * NE + (size_t)(n0 + prow) * NE + m0 + phalf;
    const unsigned short* src = &Pl[prow * 136 + phalf];
    #pragma unroll
    for (int j = 0; j < 8; ++j)
        *(uint4*)(dst + j * 8) = *(const uint4*)(src + j * 8);
}

// ---------------------------------------------------------------------------
// K2b: V[n][f] = (sum_m P[n][m] * dT[f][m]) / l[n]
// 64n x 128f tile, K=2048 in chunks of 64, single-buffered (27 KB LDS).
// ---------------------------------------------------------------------------
__global__ __launch_bounds__(256) void combine_kernel(
    const unsigned short* __restrict__ P, const unsigned short* __restrict__ dT,
    const float* __restrict__ lbuf, float* __restrict__ out, int g)
{
    __shared__ unsigned short Ps[64 * 72];
    __shared__ unsigned short Ds[128 * 72];
    const int t = threadIdx.x;
    const int hg = blockIdx.z, h = g * 4 + hg;
    const int n0 = blockIdx.y * 64, f0 = blockIdx.x * 128;
    const int wave = t >> 6, lane = t & 63, quad = lane >> 4, l16 = lane & 15;
    const unsigned short* Ph = P + (size_t)hg * NE * NE;
    const unsigned short* dh = dT + (size_t)h * 512 * NE;
    const int br = t >> 3, bcs = (t & 7) * 8;

    f32x4 acc[8];
    #pragma unroll
    for (int j = 0; j < 8; ++j) acc[j] = {0.f, 0.f, 0.f, 0.f};

    for (int mc = 0; mc < 32; ++mc) {
        #pragma unroll
        for (int p = 0; p < 2; ++p) {
            int row = br + p * 32;
            *(uint4*)&Ps[row * 72 + bcs] =
                *(const uint4*)(Ph + (size_t)(n0 + row) * NE + mc * 64 + bcs);
        }
        #pragma unroll
        for (int p = 0; p < 4; ++p) {
            int row = br + p * 32;
            *(uint4*)&Ds[row * 72 + bcs] =
                *(const uint4*)(dh + (size_t)(f0 + row) * NE + mc * 64 + bcs);
        }
        __syncthreads();
        #pragma unroll
        for (int kk = 0; kk < 2; ++kk) {
            short8 a = *(const short8*)&Ps[(wave * 16 + l16) * 72 + kk * 32 + quad * 8];
            #pragma unroll
            for (int ct = 0; ct < 8; ++ct) {
                short8 b = *(const short8*)&Ds[(ct * 16 + l16) * 72 + kk * 32 + quad * 8];
                acc[ct] = __builtin_amdgcn_mfma_f32_16x16x32_bf16(a, b, acc[ct], 0, 0, 0);
            }
        }
        __syncthreads();
    }

    const int nl = wave * 16 + quad * 4;
    #pragma unroll
    for (int reg = 0; reg < 4; ++reg) {
        float inv = 1.0f / lbuf[(size_t)h * NE + n0 + nl + reg];
        float* orow = out + (size_t)(n0 + nl + reg) * 4096 + h * 512 + f0;
        #pragma unroll
        for (int ct = 0; ct < 8; ++ct)
            orow[ct * 16 + l16] = acc[ct][reg] * inv;
    }
}

extern "C" void kernel_launch(void* const* d_in, const int* in_sizes, int n_in,
                              void* d_out, int out_size, void* d_ws, size_t ws_size,
                              hipStream_t stream)
{
    const float* x  = (const float*)d_in[0];
    const float* Qw = (const float*)d_in[1];
    const float* Kw = (const float*)d_in[2];
    const float* Dw = (const float*)d_in[3];
    float* out = (float*)d_out;

    char* ws = (char*)d_ws;
    unsigned short* xt = (unsigned short*)ws;                             // 16 MB
    unsigned short* db = (unsigned short*)(ws + 16777216);                // 16 MB
    unsigned short* P  = (unsigned short*)ws;                             // 32 MB (reuse xt+db)
    unsigned short* qb = (unsigned short*)(ws + 33554432);                // 16 MB
    unsigned short* kb = (unsigned short*)(ws + 33554432 + 16777216);     // 16 MB
    unsigned short* dT = (unsigned short*)(ws + 33554432 + 2 * 16777216); // 16 MB
    float* scales = (float*)(ws + 83886080);                              // 24 KB
    float* lbuf   = (float*)(ws + 83886080 + 32768);                      // 64 KB

    hipMemsetAsync(lbuf, 0, 8 * NE * sizeof(float), stream);
    xpose_kernel<<<2048, 256, 0, stream>>>(x, xt);
    proj_gemm<<<dim3(128, 4, 3), 256, 0, stream>>>(Qw, Kw, Dw, xt, qb, kb, db);
    scales_kernel<<<dim3(2048, 3), 256, 0, stream>>>(qb, kb, db, scales);
    dtrans_kernel<<<dim3(8, 32, 8), 256, 0, stream>>>(db, scales + 2 * NE, dT);
    for (int g = 0; g < 2; ++g) {
        score_kernel<<<dim3(16, 16, 4), 256, 0, stream>>>(qb, kb, scales, P, lbuf, g);
        combine_kernel<<<dim3(4, 32, 4), 256, 0, stream>>>(P, dT, lbuf, out, g);
    }
}